// Round 4
// baseline (597.478 us; speedup 1.0000x reference)
//
#include <hip/hip_runtime.h>

typedef unsigned short u16;
typedef unsigned int u32;
typedef unsigned long long u64;

typedef __attribute__((ext_vector_type(8))) short short8;
typedef __attribute__((ext_vector_type(4))) float float4v;

__device__ __forceinline__ float bf2f(u16 u) { return __uint_as_float(((u32)u) << 16); }
__device__ __forceinline__ u16 f2bf(float f) {
    u32 x = __float_as_uint(f);
    return (u16)((x + 0x7fffu + ((x >> 16) & 1u)) >> 16);
}
__device__ __forceinline__ float sigmoidf_(float x) { return 1.0f / (1.0f + expf(-x)); }

#define B_ 128
#define T_ 20
#define VISN 196
#define VISD 512
#define EMB 256
#define HID 512
#define VOC 10000
#define VOCP 10112   /* padded to 79*128 */
#define NBLK 64      /* recurrence grid: 2 rowgroups x 32 colgroups */
#define LDP 40       /* padded LDS stride (u16): 80B -> bank period 8, 2-way */

// fragment-major h layout: element (strip, ks, quad, mrow, e) at u16 offset
//   F = (((strip*16 + ks)*4 + quad)*16 + mrow)*8 + e
// strip = row>>4, mrow = row&15, ks = k>>5, quad = (k>>3)&3, e = k&7.
// A wave's af[ks] fragment is then one contiguous 1KB burst.

// ---------------------------------------------------------------------------
// fused weight conversion f32 -> bf16 (+ zero-pad Wo/bo to VOCP, zero flags,
// + embedding gather in bf16, time-major r = t*B+b)
// ---------------------------------------------------------------------------
__global__ __launch_bounds__(256) void conv_all(
    const float* __restrict__ Wih, const float* __restrict__ Whh,
    const float* __restrict__ Wo,  const float* __restrict__ Winh,
    const float* __restrict__ Winc, const float* __restrict__ bih,
    const float* __restrict__ bhh, const float* __restrict__ bo,
    const int* __restrict__ captions, const float* __restrict__ table,
    u16* __restrict__ cWih, u16* __restrict__ cWhh, u16* __restrict__ cWo,
    u16* __restrict__ cWinit, u16* __restrict__ cbih, u16* __restrict__ cbhh,
    u16* __restrict__ cbo, u16* __restrict__ Ebf, int* __restrict__ flags) {
    const int e0 = 1572864, e1 = 2621440, e2 = 7798784, e3 = 8060928,
              e4 = 8323072, e5 = 8325120, e6 = 8327168, e7 = 8337280,
              e8 = 8992640;   // e7 + T*B*EMB
    int gid = blockIdx.x * 256 + threadIdx.x;
    if (gid < 256) flags[gid] = 0;     // 1KB flag region (line-transposed idx)
    if (gid >= e8) return;
    if (gid < e0) { cWih[gid] = f2bf(Wih[gid]); }
    else if (gid < e1) { int l = gid - e0; cWhh[l] = f2bf(Whh[l]); }
    else if (gid < e2) {
        int l = gid - e1; int row = l >> 9, col = l & 511;
        cWo[l] = (row < VOC) ? f2bf(Wo[(size_t)row * 512 + col]) : (u16)0;
    }
    else if (gid < e3) { int l = gid - e2; cWinit[l] = f2bf(Winh[l]); }
    else if (gid < e4) { int l = gid - e3; cWinit[262144 + l] = f2bf(Winc[l]); }
    else if (gid < e5) { int l = gid - e4; cbih[l] = f2bf(bih[l]); }
    else if (gid < e6) { int l = gid - e5; cbhh[l] = f2bf(bhh[l]); }
    else if (gid < e7) { int l = gid - e6; cbo[l] = (l < VOC) ? f2bf(bo[l]) : (u16)0; }
    else {
        int l = gid - e7; int r = l >> 8, col = l & 255;
        int t = r >> 7, b = r & 127;
        int idx = captions[b * T_ + t];
        Ebf[(size_t)r * EMB + col] = f2bf(table[(size_t)idx * EMB + col]);
    }
}

// ---------------------------------------------------------------------------
// fused attention + context/fbar. One block per b.
// Phase 1: att logits (h-term softmax-invariant -> dropped), softmax -> LDS.
// Phase 2: fbar = mean_n feat, ctx = sum_n alpha*feat (features re-read,
// mostly L2-warm). Saves a launch + the alpha global round-trip.
// ---------------------------------------------------------------------------
__global__ __launch_bounds__(256) void att_ctx(const float* __restrict__ feat,
                                               const float* __restrict__ Wv,
                                               u16* __restrict__ fbar_bf,
                                               u16* __restrict__ ctx_bf) {
    __shared__ float wv[512];
    __shared__ float att[VISN];
    __shared__ float red[256];
    int b = blockIdx.x, tid = threadIdx.x;
    wv[tid] = Wv[tid];
    wv[tid + 256] = Wv[tid + 256];
    __syncthreads();
    int w = tid >> 6, lane = tid & 63;
    for (int n = w; n < VISN; n += 4) {
        const float4* fp = (const float4*)(feat + ((size_t)b * VISN + n) * VISD) + lane * 2;
        float4 a = fp[0], c = fp[1];
        const float* wp = wv + lane * 8;
        float s = a.x * wp[0] + a.y * wp[1] + a.z * wp[2] + a.w * wp[3]
                + c.x * wp[4] + c.y * wp[5] + c.z * wp[6] + c.w * wp[7];
        #pragma unroll
        for (int off = 32; off; off >>= 1) s += __shfl_down(s, off);
        if (lane == 0) att[n] = s;
    }
    __syncthreads();
    float m = -1e30f;
    for (int i = tid; i < VISN; i += 256) m = fmaxf(m, att[i]);
    red[tid] = m; __syncthreads();
    for (int s = 128; s; s >>= 1) { if (tid < s) red[tid] = fmaxf(red[tid], red[tid + s]); __syncthreads(); }
    m = red[0]; __syncthreads();
    float sum = 0.f;
    for (int i = tid; i < VISN; i += 256) { float e = expf(att[i] - m); att[i] = e; sum += e; }
    red[tid] = sum; __syncthreads();
    for (int s = 128; s; s >>= 1) { if (tid < s) red[tid] += red[tid + s]; __syncthreads(); }
    float inv = 1.0f / red[0]; __syncthreads();
    for (int i = tid; i < VISN; i += 256) att[i] *= inv;
    __syncthreads();
    // phase 2: each thread owns v = tid and v = tid+256
    #pragma unroll
    for (int half = 0; half < 2; half++) {
        int v = (half << 8) + tid;
        float accf = 0.f, accc = 0.f;
        const float* fp = feat + (size_t)b * VISN * VISD + v;
        #pragma unroll 4
        for (int n = 0; n < VISN; n++) {
            float f = fp[(size_t)n * VISD];
            accf += f;
            accc += att[n] * f;
        }
        fbar_bf[b * VISD + v] = f2bf(accf / (float)VISN);
        ctx_bf[b * VISD + v] = f2bf(accc);
    }
}

// ---------------------------------------------------------------------------
// bf16 MFMA GEMM, 64x64 tile, BK=32, PADDED LDS (stride 40 u16 = 80B ->
// fragment reads 2-way bank aliased = free; was 64B stride = 8-way).
// C = A[M,K]·B[N,K]^T + biases + addA.
// mode 0: write bf16 Cbf; mode 1: write f32 Cf; mode 2: h0c0 split
// (col<512 -> Cbf = h0 in FRAGMENT layout, else Cf = c f32 row-major).
// ---------------------------------------------------------------------------
__global__ __launch_bounds__(256) void gemm_bt(const u16* __restrict__ A, int lda,
                                               const u16* __restrict__ Bm, int ldb,
                                               int M, int N, int K,
                                               const u16* __restrict__ bias0,
                                               const u16* __restrict__ bias1,
                                               const float* __restrict__ addA, int rowmask,
                                               float* __restrict__ Cf,
                                               u16* __restrict__ Cbf, int ldc, int mode) {
    __shared__ u16 As[64 * LDP];
    __shared__ u16 Bs[64 * LDP];
    int tid = threadIdx.x;
    int n0 = blockIdx.x * 64, m0 = blockIdx.y * 64;
    int w = tid >> 6, lane = tid & 63;
    int wm = (w & 1) * 32, wn = (w >> 1) * 32;
    int mrow = lane & 15, quad = lane >> 4;
    float4v acc[2][2] = {};
    int lr = tid >> 2;
    int lc = (tid & 3) * 8;
    for (int k0 = 0; k0 < K; k0 += 32) {
        *(uint4*)(&As[lr * LDP + lc]) = *(const uint4*)(A + (size_t)(m0 + lr) * lda + k0 + lc);
        *(uint4*)(&Bs[lr * LDP + lc]) = *(const uint4*)(Bm + (size_t)(n0 + lr) * ldb + k0 + lc);
        __syncthreads();
        short8 afrag[2], bfrag[2];
        #pragma unroll
        for (int i = 0; i < 2; i++)
            afrag[i] = *(const short8*)(&As[(wm + i * 16 + mrow) * LDP + quad * 8]);
        #pragma unroll
        for (int j = 0; j < 2; j++)
            bfrag[j] = *(const short8*)(&Bs[(wn + j * 16 + mrow) * LDP + quad * 8]);
        #pragma unroll
        for (int i = 0; i < 2; i++)
            #pragma unroll
            for (int j = 0; j < 2; j++)
                acc[i][j] = __builtin_amdgcn_mfma_f32_16x16x32_bf16(afrag[i], bfrag[j], acc[i][j], 0, 0, 0);
        __syncthreads();
    }
    #pragma unroll
    for (int i = 0; i < 2; i++) {
        #pragma unroll
        for (int j = 0; j < 2; j++) {
            #pragma unroll
            for (int r = 0; r < 4; r++) {
                int grow = m0 + wm + i * 16 + quad * 4 + r;
                int gcol = n0 + wn + j * 16 + mrow;
                float v = acc[i][j][r];
                if (bias0) v += bf2f(bias0[gcol]);
                if (bias1) v += bf2f(bias1[gcol]);
                if (addA) v += addA[(size_t)(grow & rowmask) * ldc + gcol];
                if (mode == 0) {
                    Cbf[(size_t)grow * ldc + gcol] = f2bf(v);
                } else if (mode == 1) {
                    Cf[(size_t)grow * ldc + gcol] = v;
                } else {  // mode 2: h0 (fragment layout) / c0 split
                    if (gcol < 512) {
                        size_t o = ((((size_t)(grow >> 4) * 16 + (gcol >> 5)) * 4 +
                                     ((gcol >> 3) & 3)) * 16 + (grow & 15)) * 8 + (gcol & 7);
                        Cbf[o] = f2bf(v);
                    } else {
                        Cf[(size_t)grow * 512 + gcol - 512] = v;
                    }
                }
            }
        }
    }
}

// ---------------------------------------------------------------------------
// persistent fused recurrence, v5: 64 blocks = 2 rowgroups x 32 colgroups.
// v4 -> v5: h_all emit moved AFTER the flag release -- only the h ping-pong
// (fragment) stores are on the inter-block critical path; the h_all burst
// drains under the next step's barrier wait.
// ---------------------------------------------------------------------------
__global__ __launch_bounds__(256, 1) void recurrence(
    const u16* __restrict__ Whh,      // [2048,512] bf16
    const float* __restrict__ gbase,  // [2560,2048] f32 (row = t*128+b)
    const float* __restrict__ c0,     // [128,512] f32
    u16* __restrict__ h_pp,           // [2][65536] bf16 FRAGMENT layout, buf0 = h0
    u16* __restrict__ h_all,          // [2560,512] bf16 row-major
    int* __restrict__ flags) {        // 256 ints, line-transposed indexing
    __shared__ u16 Ws[64 * 520];                  // staging for W_hh slice
    __shared__ __align__(16) u16 ex[64 * 16];     // output exchange tile
    int jb = blockIdx.x, tid = threadIdx.x;
    int rg = jb >> 5, cg = jb & 31;
    // stage W_hh slice: local row lcol = g*16+q -> global row g*512+16*cg+q
    for (int idx = tid; idx < 64 * 64; idx += 256) {
        int lcol = idx >> 6, q8 = idx & 63;
        int grow = ((lcol >> 4) << 9) + (cg << 4) + (lcol & 15);
        *(uint4*)&Ws[lcol * 520 + q8 * 8] = *(const uint4*)&Whh[(size_t)grow * 512 + q8 * 8];
    }
    int w = tid >> 6, lane = tid & 63;
    int mrow = lane & 15, quad = lane >> 4;
    int rowC = (rg << 6) + (w << 4) + (quad << 2);   // C row base (+r)
    int strip = (rg << 2) + w;                       // h-fragment strip
    int colh = (cg << 4) + mrow;                     // owned h column
    float cst[4];
    #pragma unroll
    for (int r = 0; r < 4; r++) cst[r] = c0[(size_t)(rowC + r) * 512 + colh];
    __syncthreads();
    // one-time: ALL 64 B-fragments to registers (time-invariant weights)
    short8 bfv[16][4];
    #pragma unroll
    for (int ks = 0; ks < 16; ks++)
        #pragma unroll
        for (int g = 0; g < 4; g++)
            bfv[ks][g] = *(const short8*)&Ws[((g << 4) + mrow) * 520 + ks * 32 + quad * 8];
    for (int t = 0; t < T_; t++) {
        const u64* hb64 = (const u64*)(h_pp + (t & 1) * 65536);
        u16* hnxt = h_pp + ((t + 1) & 1) * 65536;
        // gbase addends for THIS step: plain cached loads, issued before the
        // poll so they drain under the barrier wait
        float gb[4][4];
        #pragma unroll
        for (int g = 0; g < 4; g++)
            #pragma unroll
            for (int r = 0; r < 4; r++)
                gb[g][r] = gbase[(size_t)(t * B_ + rowC + r) * 2048 + (g << 9) + colh];
        // barrier-at-head: wait for all rowgroup peers to release step t
        if (t > 0) {
            if (tid < 32) {
                int pj = (rg << 5) + tid;
                int fi = ((pj & 15) << 4) + (pj >> 4);
                while (__hip_atomic_load(&flags[fi], __ATOMIC_RELAXED,
                                         __HIP_MEMORY_SCOPE_AGENT) < t)
                    __builtin_amdgcn_s_sleep(1);
            }
            __syncthreads();
        }
        // A fragments: coalesced agent-scope loads from fragment-major h
        short8 af[16];
        #pragma unroll
        for (int ks = 0; ks < 16; ks++) {
            int o = (((strip * 16 + ks) * 4 + quad) * 16 + mrow) * 2;  // u64 idx
            union { u64 q[2]; short8 v; } uu;
            uu.q[0] = __hip_atomic_load(hb64 + o, __ATOMIC_RELAXED,
                                        __HIP_MEMORY_SCOPE_AGENT);
            uu.q[1] = __hip_atomic_load(hb64 + o + 1, __ATOMIC_RELAXED,
                                        __HIP_MEMORY_SCOPE_AGENT);
            af[ks] = uu.v;
        }
        float4v acc[4] = {};
        #pragma unroll
        for (int ks = 0; ks < 16; ks++)
            #pragma unroll
            for (int g = 0; g < 4; g++)
                acc[g] = __builtin_amdgcn_mfma_f32_16x16x32_bf16(af[ks], bfv[ks][g], acc[g], 0, 0, 0);
        // lane-local LSTM elementwise -> exchange tile (local [64][16])
        #pragma unroll
        for (int r = 0; r < 4; r++) {
            float ig = sigmoidf_(acc[0][r] + gb[0][r]);
            float fg = sigmoidf_(acc[1][r] + gb[1][r]);
            float gg = tanhf(acc[2][r] + gb[2][r]);
            float og = sigmoidf_(acc[3][r] + gb[3][r]);
            float cn = fg * cst[r] + ig * gg;
            cst[r] = cn;
            ex[((w << 4) + (quad << 2) + r) * 16 + mrow] = f2bf(og * tanhf(cn));
        }
        __syncthreads();
        // coalesced emit: fragment-layout h ping-pong (agent-scope dwords)
        const u32* ex32 = (const u32*)ex;
        #pragma unroll
        for (int h2 = 0; h2 < 2; h2++) {
            int d = tid + h2 * 256;
            int c = d >> 6, i = d & 63;
            int wl = c >> 1, qs = c & 1, mw = i >> 2, ep = i & 3;
            u32 val = ex32[((wl * 16 + mw) * 16 + qs * 8 + ep * 2) >> 1];
            size_t o16 = ((((size_t)((rg << 2) + wl) * 16 + (cg >> 1)) * 4 +
                          ((cg & 1) * 2 + qs)) * 16 + mw) * 8 + ep * 2;
            __hip_atomic_store((u32*)hnxt + (o16 >> 1), val,
                               __ATOMIC_RELAXED, __HIP_MEMORY_SCOPE_AGENT);
        }
        // release: drain h-pp stores, sync waves, set flag
        asm volatile("s_waitcnt vmcnt(0)" ::: "memory");
        __syncthreads();
        if (tid == 0) {
            int fi = ((jb & 15) << 4) + (jb >> 4);
            __hip_atomic_store(&flags[fi], t + 1, __ATOMIC_RELAXED,
                               __HIP_MEMORY_SCOPE_AGENT);
        }
        // h_all emit AFTER release: off the critical path; drains under the
        // next step's barrier wait. ex stays stable until the next step's
        // post-poll __syncthreads has passed, which orders all waves.
        if (tid < 128) {
            int rl = tid >> 1, hf = tid & 1;
            uint4 v = *(const uint4*)&ex[rl * 16 + hf * 8];
            *(uint4*)&h_all[(size_t)(t * B_ + (rg << 6) + rl) * 512 + (cg << 4) + hf * 8] = v;
        }
    }
}

// ---------------------------------------------------------------------------
// logits GEMM, 128x128 tile, BK=32, 4 waves each 64x64 (4x4 of 16x16x32).
// PADDED LDS (stride 40): fragment ds_read_b128 2-way aliased = free
// (was 64B stride = 8-way serialization, m98's 1.7e7-conflict signature).
// A = h_all [2560,512], B = cWo [VOCP,512] (zero-padded). C f32 -> d_out
// second half, col-guarded, + bo.
// ---------------------------------------------------------------------------
__global__ __launch_bounds__(256) void gemm128(const u16* __restrict__ A,
                                               const u16* __restrict__ Bm,
                                               const u16* __restrict__ biasbf,
                                               float* __restrict__ C) {
    __shared__ u16 As[128 * LDP];
    __shared__ u16 Bs[128 * LDP];
    int tid = threadIdx.x;
    int n0 = blockIdx.x * 128, m0 = blockIdx.y * 128;
    int w = tid >> 6, lane = tid & 63;
    int wm = (w & 1) * 64, wn = (w >> 1) * 64;
    int mrow = lane & 15, quad = lane >> 4;
    float4v acc[4][4] = {};
    for (int k0 = 0; k0 < 512; k0 += 32) {
        #pragma unroll
        for (int q = 0; q < 2; q++) {
            int idx = tid * 2 + q;              // 0..511 uint4s per matrix
            int r = idx >> 2, cc = (idx & 3) * 8;
            *(uint4*)&As[r * LDP + cc] = *(const uint4*)&A[(size_t)(m0 + r) * 512 + k0 + cc];
            *(uint4*)&Bs[r * LDP + cc] = *(const uint4*)&Bm[(size_t)(n0 + r) * 512 + k0 + cc];
        }
        __syncthreads();
        short8 af[4], bfv[4];
        #pragma unroll
        for (int i = 0; i < 4; i++)
            af[i] = *(const short8*)&As[(wm + i * 16 + mrow) * LDP + quad * 8];
        #pragma unroll
        for (int jn = 0; jn < 4; jn++)
            bfv[jn] = *(const short8*)&Bs[(wn + jn * 16 + mrow) * LDP + quad * 8];
        #pragma unroll
        for (int i = 0; i < 4; i++)
            #pragma unroll
            for (int jn = 0; jn < 4; jn++)
                acc[i][jn] = __builtin_amdgcn_mfma_f32_16x16x32_bf16(af[i], bfv[jn], acc[i][jn], 0, 0, 0);
        __syncthreads();
    }
    #pragma unroll
    for (int i = 0; i < 4; i++) {
        #pragma unroll
        for (int jn = 0; jn < 4; jn++) {
            int gcol = n0 + wn + jn * 16 + mrow;
            if (gcol >= VOC) continue;
            float bias = bf2f(biasbf[gcol]);
            #pragma unroll
            for (int r = 0; r < 4; r++) {
                int grow = m0 + wm + i * 16 + quad * 4 + r;
                C[(size_t)grow * VOC + gcol] = acc[i][jn][r] + bias;
            }
        }
    }
}

// ---------------------------------------------------------------------------
// fused log_softmax + softmax over d_out rows (f32). Raw logits in 2nd half.
// ---------------------------------------------------------------------------
__global__ __launch_bounds__(256) void softmax_out(float* __restrict__ out) {
    __shared__ float red[256];
    int r = blockIdx.x, tid = threadIdx.x;
    const size_t HALF4 = (size_t)T_ * B_ * VOC / 4;  // in float4 units
    float4* outv = (float4*)out;
    float4* src = outv + HALF4 + (size_t)r * (VOC / 4);
    float4 lv[10];
    float m = -1e30f;
    #pragma unroll
    for (int jq = 0; jq < 10; jq++) {
        int i4 = tid + jq * 256;
        if (i4 < VOC / 4) {
            float4 v = src[i4];
            lv[jq] = v;
            m = fmaxf(m, fmaxf(fmaxf(v.x, v.y), fmaxf(v.z, v.w)));
        } else {
            lv[jq] = make_float4(-1e30f, -1e30f, -1e30f, -1e30f);
        }
    }
    red[tid] = m; __syncthreads();
    for (int s = 128; s; s >>= 1) { if (tid < s) red[tid] = fmaxf(red[tid], red[tid + s]); __syncthreads(); }
    m = red[0]; __syncthreads();
    float sum = 0.f;
    #pragma unroll
    for (int jq = 0; jq < 10; jq++)
        sum += expf(lv[jq].x - m) + expf(lv[jq].y - m) + expf(lv[jq].z - m) + expf(lv[jq].w - m);
    red[tid] = sum; __syncthreads();
    for (int s = 128; s; s >>= 1) { if (tid < s) red[tid] += red[tid + s]; __syncthreads(); }
    float logZ = m + logf(red[0]);
    float4* dls = outv + (size_t)r * (VOC / 4);
    #pragma unroll
    for (int jq = 0; jq < 10; jq++) {
        int i4 = tid + jq * 256;
        if (i4 < VOC / 4) {
            float4 v = lv[jq];
            float4 ls = make_float4(v.x - logZ, v.y - logZ, v.z - logZ, v.w - logZ);
            dls[i4] = ls;
            src[i4] = make_float4(expf(ls.x), expf(ls.y), expf(ls.z), expf(ls.w));
        }
    }
}

extern "C" void kernel_launch(void* const* d_in, const int* in_sizes, int n_in,
                              void* d_out, int out_size, void* d_ws, size_t ws_size,
                              hipStream_t stream) {
    const float* features = (const float*)d_in[0];
    const int* captions   = (const int*)d_in[1];
    const float* W_init_h = (const float*)d_in[2];
    const float* W_init_c = (const float*)d_in[3];
    const float* Wv       = (const float*)d_in[4];
    // d_in[5] bv, d_in[6] Wa, d_in[7] ba unused (softmax shift-invariance)
    const float* embed_t  = (const float*)d_in[8];
    const float* W_ih     = (const float*)d_in[9];
    const float* W_hh     = (const float*)d_in[10];
    const float* b_ih     = (const float*)d_in[11];
    const float* b_hh     = (const float*)d_in[12];
    const float* Wo       = (const float*)d_in[13];
    const float* bo       = (const float*)d_in[14];
    float* out = (float*)d_out;

    // workspace layout (~43.5 MB)
    char* base = (char*)d_ws;
    int*   flags   = (int*)(base + 0);            // 1KB, line-transposed flags
    u16*   fbar_bf = (u16*)(base + 103424);
    u16*   ctx_bf  = (u16*)(base + 234496);
    u16*   h_pp    = (u16*)(base + 365568);       // 2 x 65536 bf16 (fragment)
    float* c_f32   = (float*)(base + 627712);
    float* gconst  = (float*)(base + 889856);     // [128,2048] f32
    u16*   Ebf     = (u16*)(base + 1938432);      // [2560,256] bf16
    float* gbase   = (float*)(base + 3249152);    // [2560,2048] f32
    u16*   h_all   = (u16*)(base + 24220672);     // [2560,512] bf16
    u16*   cWih    = (u16*)(base + 26842112);     // [2048,768] bf16
    u16*   cWhh    = (u16*)(base + 29987840);     // [2048,512]
    u16*   cWo     = (u16*)(base + 32084992);     // [VOCP,512] padded
    u16*   cWinit  = (u16*)(base + 42439680);     // [1024,512] (Winh;Winc)
    u16*   cbih    = (u16*)(base + 43488256);
    u16*   cbhh    = (u16*)(base + 43492352);
    u16*   cbo     = (u16*)(base + 43496448);     // [VOCP] padded

    // 1) weight conversion + embedding gather (+ flag zero)
    conv_all<<<35128, 256, 0, stream>>>(W_ih, W_hh, Wo, W_init_h, W_init_c,
                                        b_ih, b_hh, bo, captions, embed_t,
                                        cWih, cWhh, cWo, cWinit, cbih, cbhh, cbo,
                                        Ebf, flags);
    // 2) fused attention + context/mean features
    att_ctx<<<B_, 256, 0, stream>>>(features, Wv, fbar_bf, ctx_bf);
    // 3) h0 (fragment layout) | c0 = fbar @ [Winh; Winc]^T (split epilogue)
    gemm_bt<<<dim3(16, 2), 256, 0, stream>>>(
        fbar_bf, 512, cWinit, 512, B_, 1024, 512,
        nullptr, nullptr, nullptr, -1, c_f32, h_pp, 1024, 2);
    // 4) gconst = ctx @ W_ih[:, :512]^T + b_ih + b_hh   [128,2048] f32
    gemm_bt<<<dim3(32, 2), 256, 0, stream>>>(
        ctx_bf, 512, cWih, 768, B_, 2048, 512,
        cbih, cbhh, nullptr, -1, gconst, nullptr, 2048, 1);
    // 5) gbase = E @ W_ih[:, 512:768]^T + gconst[b]   [2560,2048] f32
    gemm_bt<<<dim3(32, 40), 256, 0, stream>>>(
        Ebf, 256, cWih + 512, 768, T_ * B_, 2048, 256,
        nullptr, nullptr, gconst, 127, gbase, nullptr, 2048, 1);
    // 6) fused 20-step LSTM recurrence (single persistent launch)
    recurrence<<<NBLK, 256, 0, stream>>>(cWhh, gbase, c_f32, h_pp, h_all, flags);
    // 7) logits = h_all @ Wo^T + bo -> f32 raw into d_out's second half
    gemm128<<<dim3(VOCP / 128, (T_ * B_) / 128), 256, 0, stream>>>(
        h_all, cWo, cbo, out + (size_t)T_ * B_ * VOC);
    // 8) fused log_softmax + softmax in place
    softmax_out<<<T_ * B_, 256, 0, stream>>>(out);
}

// Round 5
// 581.471 us; speedup vs baseline: 1.0275x; 1.0275x over previous
//
#include <hip/hip_runtime.h>

typedef unsigned short u16;
typedef unsigned int u32;
typedef unsigned long long u64;

typedef __attribute__((ext_vector_type(8))) short short8;
typedef __attribute__((ext_vector_type(4))) float float4v;

__device__ __forceinline__ float bf2f(u16 u) { return __uint_as_float(((u32)u) << 16); }
__device__ __forceinline__ u16 f2bf(float f) {
    u32 x = __float_as_uint(f);
    return (u16)((x + 0x7fffu + ((x >> 16) & 1u)) >> 16);
}
__device__ __forceinline__ float sigmoidf_(float x) { return 1.0f / (1.0f + expf(-x)); }

#define B_ 128
#define T_ 20
#define VISN 196
#define VISD 512
#define EMB 256
#define HID 512
#define VOC 10000
#define VOCP 10112   /* padded to 79*128 */
#define NBLK 64      /* recurrence grid: 2 rowgroups x 32 colgroups */
#define LDP 40       /* padded LDS stride (u16) for gemm_bt */

// async global->LDS, 16B per lane, wave-uniform LDS base + lane*16
#define GL16(g, l) __builtin_amdgcn_global_load_lds( \
    (const __attribute__((address_space(1))) void*)(g), \
    (__attribute__((address_space(3))) void*)(l), 16, 0, 0)

// fragment-major h layout: element (strip, ks, quad, mrow, e) at u16 offset
//   F = (((strip*16 + ks)*4 + quad)*16 + mrow)*8 + e

// ---------------------------------------------------------------------------
// fused weight conversion f32 -> bf16 (+ zero-pad Wo/bo to VOCP, zero flags,
// + embedding gather in bf16, time-major r = t*B+b)
// ---------------------------------------------------------------------------
__global__ __launch_bounds__(256) void conv_all(
    const float* __restrict__ Wih, const float* __restrict__ Whh,
    const float* __restrict__ Wo,  const float* __restrict__ Winh,
    const float* __restrict__ Winc, const float* __restrict__ bih,
    const float* __restrict__ bhh, const float* __restrict__ bo,
    const int* __restrict__ captions, const float* __restrict__ table,
    u16* __restrict__ cWih, u16* __restrict__ cWhh, u16* __restrict__ cWo,
    u16* __restrict__ cWinit, u16* __restrict__ cbih, u16* __restrict__ cbhh,
    u16* __restrict__ cbo, u16* __restrict__ Ebf, int* __restrict__ flags) {
    const int e0 = 1572864, e1 = 2621440, e2 = 7798784, e3 = 8060928,
              e4 = 8323072, e5 = 8325120, e6 = 8327168, e7 = 8337280,
              e8 = 8992640;   // e7 + T*B*EMB
    int gid = blockIdx.x * 256 + threadIdx.x;
    if (gid < 256) flags[gid] = 0;     // 1KB flag region (line-transposed idx)
    if (gid >= e8) return;
    if (gid < e0) { cWih[gid] = f2bf(Wih[gid]); }
    else if (gid < e1) { int l = gid - e0; cWhh[l] = f2bf(Whh[l]); }
    else if (gid < e2) {
        int l = gid - e1; int row = l >> 9, col = l & 511;
        cWo[l] = (row < VOC) ? f2bf(Wo[(size_t)row * 512 + col]) : (u16)0;
    }
    else if (gid < e3) { int l = gid - e2; cWinit[l] = f2bf(Winh[l]); }
    else if (gid < e4) { int l = gid - e3; cWinit[262144 + l] = f2bf(Winc[l]); }
    else if (gid < e5) { int l = gid - e4; cbih[l] = f2bf(bih[l]); }
    else if (gid < e6) { int l = gid - e5; cbhh[l] = f2bf(bhh[l]); }
    else if (gid < e7) { int l = gid - e6; cbo[l] = (l < VOC) ? f2bf(bo[l]) : (u16)0; }
    else {
        int l = gid - e7; int r = l >> 8, col = l & 255;
        int t = r >> 7, b = r & 127;
        int idx = captions[b * T_ + t];
        Ebf[(size_t)r * EMB + col] = f2bf(table[(size_t)idx * EMB + col]);
    }
}

// ---------------------------------------------------------------------------
// att: alpha[b,n] = softmax_n(features[b,n,:]·Wv). h-term of the logit is
// constant over n -> softmax-invariant -> dropped. One block per b.
// ---------------------------------------------------------------------------
__global__ __launch_bounds__(256) void att_kernel(const float* __restrict__ feat,
                                                  const float* __restrict__ Wv,
                                                  float* __restrict__ alpha) {
    __shared__ float wv[512];
    __shared__ float att[VISN];
    __shared__ float red[256];
    int b = blockIdx.x, tid = threadIdx.x;
    wv[tid] = Wv[tid];
    wv[tid + 256] = Wv[tid + 256];
    __syncthreads();
    int w = tid >> 6, lane = tid & 63;
    for (int n = w; n < VISN; n += 4) {
        const float4* fp = (const float4*)(feat + ((size_t)b * VISN + n) * VISD) + lane * 2;
        float4 a = fp[0], c = fp[1];
        const float* wp = wv + lane * 8;
        float s = a.x * wp[0] + a.y * wp[1] + a.z * wp[2] + a.w * wp[3]
                + c.x * wp[4] + c.y * wp[5] + c.z * wp[6] + c.w * wp[7];
        #pragma unroll
        for (int off = 32; off; off >>= 1) s += __shfl_down(s, off);
        if (lane == 0) att[n] = s;
    }
    __syncthreads();
    float m = -1e30f;
    for (int i = tid; i < VISN; i += 256) m = fmaxf(m, att[i]);
    red[tid] = m; __syncthreads();
    for (int s = 128; s; s >>= 1) { if (tid < s) red[tid] = fmaxf(red[tid], red[tid + s]); __syncthreads(); }
    m = red[0]; __syncthreads();
    float sum = 0.f;
    for (int i = tid; i < VISN; i += 256) { float e = expf(att[i] - m); att[i] = e; sum += e; }
    red[tid] = sum; __syncthreads();
    for (int s = 128; s; s >>= 1) { if (tid < s) red[tid] += red[tid + s]; __syncthreads(); }
    float inv = 1.0f / red[0]; __syncthreads();
    for (int i = tid; i < VISN; i += 256) alpha[b * VISN + i] = att[i] * inv;
}

// ---------------------------------------------------------------------------
// ctx/fbar: fbar = mean_n feat, ctx = sum_n alpha*feat. grid (2 vslices, 128 b)
// ---------------------------------------------------------------------------
__global__ __launch_bounds__(256) void ctx_fbar(const float* __restrict__ feat,
                                                const float* __restrict__ alpha,
                                                u16* __restrict__ fbar_bf,
                                                u16* __restrict__ ctx_bf) {
    __shared__ float al[VISN];
    int b = blockIdx.y, tid = threadIdx.x;
    int v = blockIdx.x * 256 + tid;
    if (tid < VISN) al[tid] = alpha[b * VISN + tid];
    __syncthreads();
    float accf = 0.f, accc = 0.f;
    const float* fp = feat + (size_t)b * VISN * VISD + v;
    #pragma unroll 4
    for (int n = 0; n < VISN; n++) {
        float f = fp[(size_t)n * VISD];
        accf += f;
        accc += al[n] * f;
    }
    fbar_bf[b * VISD + v] = f2bf(accf / (float)VISN);
    ctx_bf[b * VISD + v] = f2bf(accc);
}

// ---------------------------------------------------------------------------
// bf16 MFMA GEMM, 64x64 tile, BK=32, padded LDS. C = A[M,K]·B[N,K]^T + biases
// + addA. mode 0: bf16 Cbf; mode 1: f32 Cf; mode 2: h0 (FRAGMENT layout) / c0.
// ---------------------------------------------------------------------------
__global__ __launch_bounds__(256) void gemm_bt(const u16* __restrict__ A, int lda,
                                               const u16* __restrict__ Bm, int ldb,
                                               int M, int N, int K,
                                               const u16* __restrict__ bias0,
                                               const u16* __restrict__ bias1,
                                               const float* __restrict__ addA, int rowmask,
                                               float* __restrict__ Cf,
                                               u16* __restrict__ Cbf, int ldc, int mode) {
    __shared__ u16 As[64 * LDP];
    __shared__ u16 Bs[64 * LDP];
    int tid = threadIdx.x;
    int n0 = blockIdx.x * 64, m0 = blockIdx.y * 64;
    int w = tid >> 6, lane = tid & 63;
    int wm = (w & 1) * 32, wn = (w >> 1) * 32;
    int mrow = lane & 15, quad = lane >> 4;
    float4v acc[2][2] = {};
    int lr = tid >> 2;
    int lc = (tid & 3) * 8;
    for (int k0 = 0; k0 < K; k0 += 32) {
        *(uint4*)(&As[lr * LDP + lc]) = *(const uint4*)(A + (size_t)(m0 + lr) * lda + k0 + lc);
        *(uint4*)(&Bs[lr * LDP + lc]) = *(const uint4*)(Bm + (size_t)(n0 + lr) * ldb + k0 + lc);
        __syncthreads();
        short8 afrag[2], bfrag[2];
        #pragma unroll
        for (int i = 0; i < 2; i++)
            afrag[i] = *(const short8*)(&As[(wm + i * 16 + mrow) * LDP + quad * 8]);
        #pragma unroll
        for (int j = 0; j < 2; j++)
            bfrag[j] = *(const short8*)(&Bs[(wn + j * 16 + mrow) * LDP + quad * 8]);
        #pragma unroll
        for (int i = 0; i < 2; i++)
            #pragma unroll
            for (int j = 0; j < 2; j++)
                acc[i][j] = __builtin_amdgcn_mfma_f32_16x16x32_bf16(afrag[i], bfrag[j], acc[i][j], 0, 0, 0);
        __syncthreads();
    }
    #pragma unroll
    for (int i = 0; i < 2; i++) {
        #pragma unroll
        for (int j = 0; j < 2; j++) {
            #pragma unroll
            for (int r = 0; r < 4; r++) {
                int grow = m0 + wm + i * 16 + quad * 4 + r;
                int gcol = n0 + wn + j * 16 + mrow;
                float v = acc[i][j][r];
                if (bias0) v += bf2f(bias0[gcol]);
                if (bias1) v += bf2f(bias1[gcol]);
                if (addA) v += addA[(size_t)(grow & rowmask) * ldc + gcol];
                if (mode == 0) {
                    Cbf[(size_t)grow * ldc + gcol] = f2bf(v);
                } else if (mode == 1) {
                    Cf[(size_t)grow * ldc + gcol] = v;
                } else {  // mode 2: h0 (fragment layout) / c0 split
                    if (gcol < 512) {
                        size_t o = ((((size_t)(grow >> 4) * 16 + (gcol >> 5)) * 4 +
                                     ((gcol >> 3) & 3)) * 16 + (grow & 15)) * 8 + (gcol & 7);
                        Cbf[o] = f2bf(v);
                    } else {
                        Cf[(size_t)grow * 512 + gcol - 512] = v;
                    }
                }
            }
        }
    }
}

// ---------------------------------------------------------------------------
// persistent fused recurrence, v5 (unchanged from R4): 64 blocks =
// 2 rowgroups x 32 colgroups; reg-resident W_hh; fragment-major h ping-pong;
// relaxed agent-scope comm; h_all emitted after the flag release.
// ---------------------------------------------------------------------------
__global__ __launch_bounds__(256, 1) void recurrence(
    const u16* __restrict__ Whh,      // [2048,512] bf16
    const float* __restrict__ gbase,  // [2560,2048] f32 (row = t*128+b)
    const float* __restrict__ c0,     // [128,512] f32
    u16* __restrict__ h_pp,           // [2][65536] bf16 FRAGMENT layout, buf0 = h0
    u16* __restrict__ h_all,          // [2560,512] bf16 row-major
    int* __restrict__ flags) {        // 256 ints, line-transposed indexing
    __shared__ u16 Ws[64 * 520];                  // staging for W_hh slice
    __shared__ __align__(16) u16 ex[64 * 16];     // output exchange tile
    int jb = blockIdx.x, tid = threadIdx.x;
    int rg = jb >> 5, cg = jb & 31;
    for (int idx = tid; idx < 64 * 64; idx += 256) {
        int lcol = idx >> 6, q8 = idx & 63;
        int grow = ((lcol >> 4) << 9) + (cg << 4) + (lcol & 15);
        *(uint4*)&Ws[lcol * 520 + q8 * 8] = *(const uint4*)&Whh[(size_t)grow * 512 + q8 * 8];
    }
    int w = tid >> 6, lane = tid & 63;
    int mrow = lane & 15, quad = lane >> 4;
    int rowC = (rg << 6) + (w << 4) + (quad << 2);   // C row base (+r)
    int strip = (rg << 2) + w;                       // h-fragment strip
    int colh = (cg << 4) + mrow;                     // owned h column
    float cst[4];
    #pragma unroll
    for (int r = 0; r < 4; r++) cst[r] = c0[(size_t)(rowC + r) * 512 + colh];
    __syncthreads();
    short8 bfv[16][4];
    #pragma unroll
    for (int ks = 0; ks < 16; ks++)
        #pragma unroll
        for (int g = 0; g < 4; g++)
            bfv[ks][g] = *(const short8*)&Ws[((g << 4) + mrow) * 520 + ks * 32 + quad * 8];
    for (int t = 0; t < T_; t++) {
        const u64* hb64 = (const u64*)(h_pp + (t & 1) * 65536);
        u16* hnxt = h_pp + ((t + 1) & 1) * 65536;
        float gb[4][4];
        #pragma unroll
        for (int g = 0; g < 4; g++)
            #pragma unroll
            for (int r = 0; r < 4; r++)
                gb[g][r] = gbase[(size_t)(t * B_ + rowC + r) * 2048 + (g << 9) + colh];
        if (t > 0) {
            if (tid < 32) {
                int pj = (rg << 5) + tid;
                int fi = ((pj & 15) << 4) + (pj >> 4);
                while (__hip_atomic_load(&flags[fi], __ATOMIC_RELAXED,
                                         __HIP_MEMORY_SCOPE_AGENT) < t)
                    __builtin_amdgcn_s_sleep(1);
            }
            __syncthreads();
        }
        short8 af[16];
        #pragma unroll
        for (int ks = 0; ks < 16; ks++) {
            int o = (((strip * 16 + ks) * 4 + quad) * 16 + mrow) * 2;  // u64 idx
            union { u64 q[2]; short8 v; } uu;
            uu.q[0] = __hip_atomic_load(hb64 + o, __ATOMIC_RELAXED,
                                        __HIP_MEMORY_SCOPE_AGENT);
            uu.q[1] = __hip_atomic_load(hb64 + o + 1, __ATOMIC_RELAXED,
                                        __HIP_MEMORY_SCOPE_AGENT);
            af[ks] = uu.v;
        }
        float4v acc[4] = {};
        #pragma unroll
        for (int ks = 0; ks < 16; ks++)
            #pragma unroll
            for (int g = 0; g < 4; g++)
                acc[g] = __builtin_amdgcn_mfma_f32_16x16x32_bf16(af[ks], bfv[ks][g], acc[g], 0, 0, 0);
        #pragma unroll
        for (int r = 0; r < 4; r++) {
            float ig = sigmoidf_(acc[0][r] + gb[0][r]);
            float fg = sigmoidf_(acc[1][r] + gb[1][r]);
            float gg = tanhf(acc[2][r] + gb[2][r]);
            float og = sigmoidf_(acc[3][r] + gb[3][r]);
            float cn = fg * cst[r] + ig * gg;
            cst[r] = cn;
            ex[((w << 4) + (quad << 2) + r) * 16 + mrow] = f2bf(og * tanhf(cn));
        }
        __syncthreads();
        const u32* ex32 = (const u32*)ex;
        #pragma unroll
        for (int h2 = 0; h2 < 2; h2++) {
            int d = tid + h2 * 256;
            int c = d >> 6, i = d & 63;
            int wl = c >> 1, qs = c & 1, mw = i >> 2, ep = i & 3;
            u32 val = ex32[((wl * 16 + mw) * 16 + qs * 8 + ep * 2) >> 1];
            size_t o16 = ((((size_t)((rg << 2) + wl) * 16 + (cg >> 1)) * 4 +
                          ((cg & 1) * 2 + qs)) * 16 + mw) * 8 + ep * 2;
            __hip_atomic_store((u32*)hnxt + (o16 >> 1), val,
                               __ATOMIC_RELAXED, __HIP_MEMORY_SCOPE_AGENT);
        }
        asm volatile("s_waitcnt vmcnt(0)" ::: "memory");
        __syncthreads();
        if (tid == 0) {
            int fi = ((jb & 15) << 4) + (jb >> 4);
            __hip_atomic_store(&flags[fi], t + 1, __ATOMIC_RELAXED,
                               __HIP_MEMORY_SCOPE_AGENT);
        }
        if (tid < 128) {
            int rl = tid >> 1, hf = tid & 1;
            uint4 v = *(const uint4*)&ex[rl * 16 + hf * 8];
            *(uint4*)&h_all[(size_t)(t * B_ + (rg << 6) + rl) * 512 + (cg << 4) + hf * 8] = v;
        }
    }
}

// ---------------------------------------------------------------------------
// logits GEMM, v2 (m97-style): 128x128 tile, BK=32, LINEAR LDS, staging via
// width-16 global_load_lds (wave-uniform LDS base + lane*16B; per-lane global
// src). No register staging, no store->barrier round trip.
// A = h_all [2560,512], B = cWo [VOCP,512] (zero-padded). C f32 -> d_out
// second half, col-guarded, + bo.
// ---------------------------------------------------------------------------
__global__ __launch_bounds__(256) void gemm128(const u16* __restrict__ A,
                                               const u16* __restrict__ Bm,
                                               const u16* __restrict__ biasbf,
                                               float* __restrict__ C) {
    __shared__ u16 As[128 * 32];
    __shared__ u16 Bs[128 * 32];
    int tid = threadIdx.x;
    int n0 = blockIdx.x * 128, m0 = blockIdx.y * 128;
    int w = tid >> 6, lane = tid & 63;
    int wm = (w & 1) * 64, wn = (w >> 1) * 64;
    int mrow = lane & 15, quad = lane >> 4;
    int sr = lane >> 2;             // row within 16-row band
    int sc = (lane & 3) * 8;        // u16 col
    const u16* Ab = A + (size_t)(m0 + w * 16 + sr) * 512 + sc;
    const u16* Bb = Bm + (size_t)(n0 + w * 16 + sr) * 512 + sc;
    u16* AsW = &As[w * 16 * 32];    // wave-uniform LDS bases
    u16* BsW = &Bs[w * 16 * 32];
    float4v acc[4][4] = {};
    for (int k0 = 0; k0 < 512; k0 += 32) {
        GL16(Ab + k0, AsW);
        GL16(Ab + 64 * 512 + k0, AsW + 64 * 32);
        GL16(Bb + k0, BsW);
        GL16(Bb + 64 * 512 + k0, BsW + 64 * 32);
        asm volatile("s_waitcnt vmcnt(0)" ::: "memory");
        __syncthreads();
        short8 af[4], bfv[4];
        #pragma unroll
        for (int i = 0; i < 4; i++)
            af[i] = *(const short8*)&As[(wm + i * 16 + mrow) * 32 + quad * 8];
        #pragma unroll
        for (int jn = 0; jn < 4; jn++)
            bfv[jn] = *(const short8*)&Bs[(wn + jn * 16 + mrow) * 32 + quad * 8];
        #pragma unroll
        for (int i = 0; i < 4; i++)
            #pragma unroll
            for (int jn = 0; jn < 4; jn++)
                acc[i][jn] = __builtin_amdgcn_mfma_f32_16x16x32_bf16(af[i], bfv[jn], acc[i][jn], 0, 0, 0);
        __syncthreads();
    }
    #pragma unroll
    for (int i = 0; i < 4; i++) {
        #pragma unroll
        for (int jn = 0; jn < 4; jn++) {
            int gcol = n0 + wn + jn * 16 + mrow;
            if (gcol >= VOC) continue;
            float bias = bf2f(biasbf[gcol]);
            #pragma unroll
            for (int r = 0; r < 4; r++) {
                int grow = m0 + wm + i * 16 + quad * 4 + r;
                C[(size_t)grow * VOC + gcol] = acc[i][jn][r] + bias;
            }
        }
    }
}

// ---------------------------------------------------------------------------
// fused log_softmax + softmax over d_out rows (f32). Raw logits in 2nd half.
// ---------------------------------------------------------------------------
__global__ __launch_bounds__(256) void softmax_out(float* __restrict__ out) {
    __shared__ float red[256];
    int r = blockIdx.x, tid = threadIdx.x;
    const size_t HALF4 = (size_t)T_ * B_ * VOC / 4;  // in float4 units
    float4* outv = (float4*)out;
    float4* src = outv + HALF4 + (size_t)r * (VOC / 4);
    float4 lv[10];
    float m = -1e30f;
    #pragma unroll
    for (int jq = 0; jq < 10; jq++) {
        int i4 = tid + jq * 256;
        if (i4 < VOC / 4) {
            float4 v = src[i4];
            lv[jq] = v;
            m = fmaxf(m, fmaxf(fmaxf(v.x, v.y), fmaxf(v.z, v.w)));
        } else {
            lv[jq] = make_float4(-1e30f, -1e30f, -1e30f, -1e30f);
        }
    }
    red[tid] = m; __syncthreads();
    for (int s = 128; s; s >>= 1) { if (tid < s) red[tid] = fmaxf(red[tid], red[tid + s]); __syncthreads(); }
    m = red[0]; __syncthreads();
    float sum = 0.f;
    #pragma unroll
    for (int jq = 0; jq < 10; jq++)
        sum += expf(lv[jq].x - m) + expf(lv[jq].y - m) + expf(lv[jq].z - m) + expf(lv[jq].w - m);
    red[tid] = sum; __syncthreads();
    for (int s = 128; s; s >>= 1) { if (tid < s) red[tid] += red[tid + s]; __syncthreads(); }
    float logZ = m + logf(red[0]);
    float4* dls = outv + (size_t)r * (VOC / 4);
    #pragma unroll
    for (int jq = 0; jq < 10; jq++) {
        int i4 = tid + jq * 256;
        if (i4 < VOC / 4) {
            float4 v = lv[jq];
            float4 ls = make_float4(v.x - logZ, v.y - logZ, v.z - logZ, v.w - logZ);
            dls[i4] = ls;
            src[i4] = make_float4(expf(ls.x), expf(ls.y), expf(ls.z), expf(ls.w));
        }
    }
}

extern "C" void kernel_launch(void* const* d_in, const int* in_sizes, int n_in,
                              void* d_out, int out_size, void* d_ws, size_t ws_size,
                              hipStream_t stream) {
    const float* features = (const float*)d_in[0];
    const int* captions   = (const int*)d_in[1];
    const float* W_init_h = (const float*)d_in[2];
    const float* W_init_c = (const float*)d_in[3];
    const float* Wv       = (const float*)d_in[4];
    // d_in[5] bv, d_in[6] Wa, d_in[7] ba unused (softmax shift-invariance)
    const float* embed_t  = (const float*)d_in[8];
    const float* W_ih     = (const float*)d_in[9];
    const float* W_hh     = (const float*)d_in[10];
    const float* b_ih     = (const float*)d_in[11];
    const float* b_hh     = (const float*)d_in[12];
    const float* Wo       = (const float*)d_in[13];
    const float* bo       = (const float*)d_in[14];
    float* out = (float*)d_out;

    // workspace layout (~43.5 MB)
    char* base = (char*)d_ws;
    int*   flags   = (int*)(base + 0);            // 1KB, line-transposed flags
    float* alpha   = (float*)(base + 1024);       // [128,196] f32
    u16*   fbar_bf = (u16*)(base + 103424);
    u16*   ctx_bf  = (u16*)(base + 234496);
    u16*   h_pp    = (u16*)(base + 365568);       // 2 x 65536 bf16 (fragment)
    float* c_f32   = (float*)(base + 627712);
    float* gconst  = (float*)(base + 889856);     // [128,2048] f32
    u16*   Ebf     = (u16*)(base + 1938432);      // [2560,256] bf16
    float* gbase   = (float*)(base + 3249152);    // [2560,2048] f32
    u16*   h_all   = (u16*)(base + 24220672);     // [2560,512] bf16
    u16*   cWih    = (u16*)(base + 26842112);     // [2048,768] bf16
    u16*   cWhh    = (u16*)(base + 29987840);     // [2048,512]
    u16*   cWo     = (u16*)(base + 32084992);     // [VOCP,512] padded
    u16*   cWinit  = (u16*)(base + 42439680);     // [1024,512] (Winh;Winc)
    u16*   cbih    = (u16*)(base + 43488256);
    u16*   cbhh    = (u16*)(base + 43492352);
    u16*   cbo     = (u16*)(base + 43496448);     // [VOCP] padded

    // 1) weight conversion + embedding gather (+ flag zero)
    conv_all<<<35128, 256, 0, stream>>>(W_ih, W_hh, Wo, W_init_h, W_init_c,
                                        b_ih, b_hh, bo, captions, embed_t,
                                        cWih, cWhh, cWo, cWinit, cbih, cbhh, cbo,
                                        Ebf, flags);
    // 2) attention weights + context/mean features (full-width parallelism)
    att_kernel<<<B_, 256, 0, stream>>>(features, Wv, alpha);
    ctx_fbar<<<dim3(2, B_), 256, 0, stream>>>(features, alpha, fbar_bf, ctx_bf);
    // 3) h0 (fragment layout) | c0 = fbar @ [Winh; Winc]^T (split epilogue)
    gemm_bt<<<dim3(16, 2), 256, 0, stream>>>(
        fbar_bf, 512, cWinit, 512, B_, 1024, 512,
        nullptr, nullptr, nullptr, -1, c_f32, h_pp, 1024, 2);
    // 4) gconst = ctx @ W_ih[:, :512]^T + b_ih + b_hh   [128,2048] f32
    gemm_bt<<<dim3(32, 2), 256, 0, stream>>>(
        ctx_bf, 512, cWih, 768, B_, 2048, 512,
        cbih, cbhh, nullptr, -1, gconst, nullptr, 2048, 1);
    // 5) gbase = E @ W_ih[:, 512:768]^T + gconst[b]   [2560,2048] f32
    gemm_bt<<<dim3(32, 40), 256, 0, stream>>>(
        Ebf, 256, cWih + 512, 768, T_ * B_, 2048, 256,
        nullptr, nullptr, gconst, 127, gbase, nullptr, 2048, 1);
    // 6) fused 20-step LSTM recurrence (single persistent launch)
    recurrence<<<NBLK, 256, 0, stream>>>(cWhh, gbase, c_f32, h_pp, h_all, flags);
    // 7) logits = h_all @ Wo^T + bo -> f32 raw into d_out's second half
    gemm128<<<dim3(VOCP / 128, (T_ * B_) / 128), 256, 0, stream>>>(
        h_all, cWo, cbo, out + (size_t)T_ * B_ * VOC);
    // 8) fused log_softmax + softmax in place
    softmax_out<<<T_ * B_, 256, 0, stream>>>(out);
}